// Round 5
// baseline (473.141 us; speedup 1.0000x reference)
//
#include <hip/hip_runtime.h>

#define NLAYER 7
#define IMGB 16384          // bytes per weight-layer image: A[n][k] fp8, plain row-major
#define WSCALE 16.0f        // weights stored x16 (e4m3 subnormal protection)

typedef __attribute__((ext_vector_type(2))) float float2v;
typedef __attribute__((ext_vector_type(4))) float float4v;
typedef __attribute__((ext_vector_type(4))) unsigned int uint4v;
typedef unsigned long long u64;

__device__ __forceinline__ float2v pk_fma(float2v a, float2v b, float2v c){
  return __builtin_elementwise_fma(a, b, c);
}
__device__ __forceinline__ float2v lo2(float4v v){ return (float2v){v[0], v[1]}; }
__device__ __forceinline__ float2v hi2(float4v v){ return (float2v){v[2], v[3]}; }

// pack 4 f32 -> 4 fp8 e4m3 bytes (ascending)
__device__ __forceinline__ unsigned pk4fp8(float v0, float v1, float v2, float v3){
  int w = __builtin_amdgcn_cvt_pk_fp8_f32(v0, v1, 0, false);
  w = __builtin_amdgcn_cvt_pk_fp8_f32(v2, v3, w, true);
  return (unsigned)w;
}
template<bool HI>
__device__ __forceinline__ float2v up2(unsigned w){
  return __builtin_amdgcn_cvt_pk_f32_fp8((int)w, HI);
}
__device__ __forceinline__ float4v mfma8(u64 a, u64 b, float4v c){
  return __builtin_amdgcn_mfma_f32_16x16x32_fp8_fp8((long)a, (long)b, c, 0, 0, 0);
}
// P16 = 16*Phi(z) (cubic Taylor), gp16 = 16*gelu'(z)  -- used at natural scale (L0)
__device__ __forceinline__ void act2(float2v z, float2v& P16, float2v& gp16){
  const float2v c1v  = {6.3830764862829235f, 6.3830764862829235f};
  const float2v c3v  = {-1.0638460810704874f, -1.0638460810704874f};
  const float2v c33v = {-3.1915382432114624f, -3.1915382432114624f};
  const float2v v8   = {8.f, 8.f};
  float2v z2 = z * z;
  float2v u  = pk_fma(z2, c3v, c1v);
  P16 = pk_fma(z, u, v8);
  float2v Pd = pk_fma(z2, c33v, c1v);
  gp16 = pk_fma(z, Pd, P16);
}

// ---- prep: Wh fp32 [side][term][L][k][n] -> fp8 image [net][L][n][k], W*16 ----
// 28 blocks (net,L). Phase A: coalesced f32 row reads -> fp8 -> LDS [k][n].
// Phase B: byte-gather transpose -> coalesced b64 row writes.
__global__ __launch_bounds__(256)
void prep_weights(const float* __restrict__ lWh,
                  const float* __restrict__ rWh,
                  unsigned char* __restrict__ wbf)
{
  __shared__ __align__(16) unsigned char T[IMGB];
  const int b = blockIdx.x;               // net*7 + L
  const int net = b / NLAYER, L = b % NLAYER;
  const int side = net >> 1, term = net & 1;
  const float* src = (side ? rWh : lWh) + (size_t)((term*NLAYER + L)*128)*128;
  const int t = threadIdx.x;
  {
    const int k = t >> 1, n0 = (t & 1)*64;
    const float* row = src + k*128 + n0;
    #pragma unroll
    for (int c4 = 0; c4 < 4; ++c4){
      float4v f0 = *(const float4v*)(row + c4*16);
      float4v f1 = *(const float4v*)(row + c4*16 + 4);
      float4v f2 = *(const float4v*)(row + c4*16 + 8);
      float4v f3 = *(const float4v*)(row + c4*16 + 12);
      uint4v wv = { pk4fp8(f0[0]*WSCALE, f0[1]*WSCALE, f0[2]*WSCALE, f0[3]*WSCALE),
                    pk4fp8(f1[0]*WSCALE, f1[1]*WSCALE, f1[2]*WSCALE, f1[3]*WSCALE),
                    pk4fp8(f2[0]*WSCALE, f2[1]*WSCALE, f2[2]*WSCALE, f2[3]*WSCALE),
                    pk4fp8(f3[0]*WSCALE, f3[1]*WSCALE, f3[2]*WSCALE, f3[3]*WSCALE) };
      *(uint4v*)&T[k*128 + n0 + c4*16] = wv;
    }
  }
  __syncthreads();
  {
    const int n = t >> 1, c0 = (t & 1)*8;
    unsigned char* dst = wbf + ((size_t)b << 14) + n*128;
    #pragma unroll
    for (int c = 0; c < 8; ++c){
      const int kc = (c0 + c)*8;
      u64 v = 0;
      #pragma unroll
      for (int j = 0; j < 8; ++j)
        v |= (u64)T[(kc + j)*128 + n] << (8*j);
      *(u64*)(dst + (c0 + c)*8) = v;
    }
  }
}

__global__ __launch_bounds__(256, 4)
void sympl_main(const float* __restrict__ X,
                const float* __restrict__ lW0, const float* __restrict__ lb0,
                const float* __restrict__ lbh, const float* __restrict__ lWo,
                const float* __restrict__ rW0, const float* __restrict__ rb0,
                const float* __restrict__ rbh, const float* __restrict__ rWo,
                const int* __restrict__ lidx, const int* __restrict__ ridx,
                const unsigned char* __restrict__ wbf,
                float* __restrict__ out)
{
  // double-buffered activations; buf: rows 0-31 S_h, 32-63 S_d
  // element row e, byte-chunk c: addr = e*128 + (c ^ (e&15))*8
  __shared__ __align__(16) unsigned char sH[2][8192];

  const int tid  = threadIdx.x;
  const int lane = tid & 63;
  const int w    = tid >> 6;
  const int m0   = lane & 15;
  const int q    = lane >> 4;
  const int g    = w & 1;          // element group (0:0-15, 1:16-31)
  const int ih   = w >> 1;         // n_out half (tiles ih*4 .. ih*4+3)
  const int col  = blockIdx.y;
  const int e0   = blockIdx.x * 32;
  const int r    = tid >> 3;       // element 0..31 (8 threads each)
  const int sg   = tid & 7;
  const int rs   = r & 15;
  const int voff = (ih*64 + m0)*128 + q*8;   // a-frag byte offset within image

  const int lt = (lidx[0] == col) ? 0 : 1;
  const int rt = (ridx[0] == col) ? 0 : 1;

  float qv = X[(e0 + r)*4 + col];
  float pv = X[(e0 + r)*4 + 2 + col];

  const float dt = 0.1f;
  const float C0 = 0.6756035959798289f, C1 = -0.17560359597982883f;
  const float D0 = 1.3512071919596578f, D1 = -1.7024143839193153f;
  const float is = 1.0f / 262144.0f;   // unwind final S_d scale 16*4^7
  const float coefs[7] = { C0*dt*is, -D0*dt*is, C1*dt*is, -D1*dt*is,
                           C1*dt*is, -D0*dt*is, C0*dt*is };

  // folded-scale epilogue constants (polynomials in u = 256*z)
  const float2v v256 = {256.f, 256.f};
  const float2v K0 = {0.03125f, 0.03125f};                      // Sh = u*(K0 + K1 u + K3 u^3)
  const float2v K1 = {9.739801768e-5f, 9.739801768e-5f};
  const float2v K3 = {-2.476767495e-10f, -2.476767495e-10f};
  const float2v G0 = {0.125f, 0.125f};                          // Sd = acc1*(G0 + G1 u + G3 u^3)
  const float2v G1 = {7.791841414e-4f, 7.791841414e-4f};
  const float2v G3 = {-3.962875977e-9f, -3.962875977e-9f};

  // a-frags in registers: [i][ks]
  u64 a[4][4];
  {
    const unsigned char* img = wbf + (size_t)(2 + rt)*NLAYER*IMGB;   // ev0 L=0
    #pragma unroll
    for (int i = 0; i < 4; ++i)
      #pragma unroll
      for (int ks = 0; ks < 4; ++ks)
        a[i][ks] = *(const u64*)(img + voff + i*2048 + ks*32);
  }

  for (int ev = 0; ev < 7; ++ev){
    const bool isT = !(ev & 1);
    const int  term = isT ? rt : lt;
    const float* W0p = (isT ? rW0 : lW0) + term*128;
    const float* b0p = (isT ? rb0 : lb0) + term*128;
    const float* bhp = (isT ? rbh : lbh) + term*NLAYER*128;
    const float* Wop = (isT ? rWo : lWo) + term*128;
    const unsigned char* wimg = wbf + (size_t)(((isT ? 2 : 0) + term)*NLAYER)*IMGB;
    const int tnx = (ev & 1) ? rt : lt;
    const unsigned char* wimg_nx = wbf + (size_t)((((ev & 1) ? 2 : 0) + tnx)*NLAYER)*IMGB;

    // ---- layer 0 -> sH[0]: S_h = 16*gelu(z), S_d = 16*gelu'(z)*w, z = x*w+b ----
    {
      const float x = isT ? pv : qv;
      const float2v xv = {x, x};
      unsigned char* pH = sH[0] + r*128;
      unsigned char* pD = pH + 4096;
      #pragma unroll
      for (int c = 0; c < 2; ++c){
        int n0 = sg*16 + c*8;
        float4v wa = *(const float4v*)(W0p + n0);
        float4v wb = *(const float4v*)(W0p + n0 + 4);
        float4v ba = *(const float4v*)(b0p + n0);
        float4v bb = *(const float4v*)(b0p + n0 + 4);
        float2v zp[4] = { pk_fma(xv, lo2(wa), lo2(ba)), pk_fma(xv, hi2(wa), hi2(ba)),
                          pk_fma(xv, lo2(wb), lo2(bb)), pk_fma(xv, hi2(wb), hi2(bb)) };
        float2v wp[4] = { lo2(wa), hi2(wa), lo2(wb), hi2(wb) };
        float Sh[8], Sd[8];
        #pragma unroll
        for (int pp = 0; pp < 4; ++pp){
          float2v P16, gp16; act2(zp[pp], P16, gp16);
          float2v h = zp[pp] * P16;
          float2v d = gp16 * wp[pp];
          Sh[pp*2] = h[0]; Sh[pp*2+1] = h[1];
          Sd[pp*2] = d[0]; Sd[pp*2+1] = d[1];
        }
        u64 hv = (u64)pk4fp8(Sh[0],Sh[1],Sh[2],Sh[3]) | ((u64)pk4fp8(Sh[4],Sh[5],Sh[6],Sh[7]) << 32);
        u64 dv = (u64)pk4fp8(Sd[0],Sd[1],Sd[2],Sd[3]) | ((u64)pk4fp8(Sd[4],Sd[5],Sd[6],Sd[7]) << 32);
        int off = ((2*sg + c) ^ rs) * 8;
        *(u64*)(pH + off) = hv;
        *(u64*)(pD + off) = dv;
      }
    }
    __syncthreads();

    // ---- hidden layers: one barrier per layer (sH ping-pong, weights in regs) ----
    for (int L = 0; L < NLAYER; ++L){
      const unsigned char* pB0 = sH[L & 1] + (g*16 + m0)*128;
      const unsigned char* pB1 = pB0 + 4096;

      float4v acc[4][2];
      #pragma unroll
      for (int i = 0; i < 4; ++i){
        acc[i][0] = (float4v){0.f,0.f,0.f,0.f};
        acc[i][1] = (float4v){0.f,0.f,0.f,0.f};
      }
      #pragma unroll
      for (int ks = 0; ks < 4; ++ks){
        const int co = ((ks*4 + q) ^ m0) * 8;
        u64 b0 = *(const u64*)(pB0 + co);
        u64 b1 = *(const u64*)(pB1 + co);
        #pragma unroll
        for (int i = 0; i < 4; ++i){
          acc[i][0] = mfma8(a[i][ks], b0, acc[i][0]);
          acc[i][1] = mfma8(a[i][ks], b1, acc[i][1]);
        }
      }

      // prefetch next layer's a-frags (VMEM, overlaps epilogue + barrier)
      if (!(ev == 6 && L == 6)){
        const unsigned char* nimg = (L < 6) ? (wimg + (size_t)(L+1)*IMGB) : wimg_nx;
        #pragma unroll
        for (int i = 0; i < 4; ++i)
          #pragma unroll
          for (int ks = 0; ks < 4; ++ks)
            a[i][ks] = *(const u64*)(nimg + voff + i*2048 + ks*32);
      }

      // epilogue -> other buffer; u = acc0 + 256*b, folded-scale polys
      unsigned char* pHe = sH[(L+1) & 1] + (g*16 + m0)*128;
      unsigned char* pDe = pHe + 4096;
      const float* bias = bhp + L*128;
      const bool last = (L == NLAYER-1);
      #pragma unroll
      for (int i = 0; i < 4; ++i){
        const int I = ih*4 + i;
        float4v bv = *(const float4v*)(bias + I*16 + q*4);
        float2v ua = pk_fma(lo2(bv), v256, lo2(acc[i][0]));
        float2v ub = pk_fma(hi2(bv), v256, hi2(acc[i][0]));
        float2v u2a = ua * ua, u2b = ub * ub;
        float2v ga = pk_fma(ua, pk_fma(u2a, G3, G1), G0);
        float2v gb = pk_fma(ub, pk_fma(u2b, G3, G1), G0);
        float2v da = ga * lo2(acc[i][1]);
        float2v db = gb * hi2(acc[i][1]);
        const int off = ((I*2 + (q >> 1)) ^ m0) * 8 + (q & 1) * 4;
        if (!last){
          float2v ha = ua * pk_fma(ua, pk_fma(u2a, K3, K1), K0);
          float2v hb = ub * pk_fma(ub, pk_fma(u2b, K3, K1), K0);
          *(unsigned*)(pHe + off) = pk4fp8(ha[0], ha[1], hb[0], hb[1]);
        }
        *(unsigned*)(pDe + off) = pk4fp8(da[0], da[1], db[0], db[1]);
      }
      __syncthreads();   // sH[(L+1)&1] ready; prefetched a[] not yet needed
    }

    // ---- reduce: s_raw = S_d7 . Wo  (= 262144 * s); S_d7 lives in sH[1] ----
    {
      const unsigned char* pD = sH[1] + 4096 + r*128;
      float2v sv = {0.f, 0.f};
      #pragma unroll
      for (int c = 0; c < 2; ++c){
        u64 dv8 = *(const u64*)(pD + ((2*sg + c) ^ rs) * 8);
        unsigned wlo = (unsigned)dv8, whi = (unsigned)(dv8 >> 32);
        float4v woa = *(const float4v*)(Wop + sg*16 + c*8);
        float4v wob = *(const float4v*)(Wop + sg*16 + c*8 + 4);
        sv = pk_fma(up2<false>(wlo), lo2(woa), sv);
        sv = pk_fma(up2<true>(wlo),  hi2(woa), sv);
        sv = pk_fma(up2<false>(whi), lo2(wob), sv);
        sv = pk_fma(up2<true>(whi),  hi2(wob), sv);
      }
      float s = sv[0] + sv[1];
      s += __shfl_xor(s, 1);
      s += __shfl_xor(s, 2);
      s += __shfl_xor(s, 4);
      if (isT) qv += coefs[ev] * s;
      else     pv += coefs[ev] * s;
    }
    // no barrier: next L0 writes sH[0], last read before this eval's L6 barrier;
    // reduce reads sH[1], next overwrite of sH[1] is after the next post-L0 barrier.
  }

  if (sg == 0){
    out[(e0 + r)*4 + col]     = qv;
    out[(e0 + r)*4 + 2 + col] = pv;
  }
}

extern "C" void kernel_launch(void* const* d_in, const int* in_sizes, int n_in,
                              void* d_out, int out_size, void* d_ws, size_t ws_size,
                              hipStream_t stream)
{
  const float* X   = (const float*)d_in[0];
  const float* lW0 = (const float*)d_in[1];
  const float* lb0 = (const float*)d_in[2];
  const float* lWh = (const float*)d_in[3];
  const float* lbh = (const float*)d_in[4];
  const float* lWo = (const float*)d_in[5];
  const float* rW0 = (const float*)d_in[7];
  const float* rb0 = (const float*)d_in[8];
  const float* rWh = (const float*)d_in[9];
  const float* rbh = (const float*)d_in[10];
  const float* rWo = (const float*)d_in[11];
  const int*   li  = (const int*)d_in[13];
  const int*   ri  = (const int*)d_in[14];
  unsigned char* wbf = (unsigned char*)d_ws;   // 4*7*16384 B = 458752 B
  float* out = (float*)d_out;
  const int B = in_sizes[0] / 4;

  hipLaunchKernelGGL(prep_weights, dim3(4*NLAYER), dim3(256), 0, stream,
                     lWh, rWh, wbf);
  hipLaunchKernelGGL(sympl_main, dim3(B/32, 2), dim3(256), 0, stream,
                     X, lW0, lb0, lbh, lWo, rW0, rb0, rbh, rWo, li, ri, wbf, out);
}

// Round 6
// 203.048 us; speedup vs baseline: 2.3302x; 2.3302x over previous
//
#include <hip/hip_runtime.h>

#define NLAYER 7
#define IMGB 16384          // bytes per weight-layer image: A[n][k] fp8, 8B-chunk XOR-swizzled
#define WSCALE 16.0f        // weights stored x16 (e4m3 subnormal protection)

typedef __attribute__((ext_vector_type(2))) float float2v;
typedef __attribute__((ext_vector_type(4))) float float4v;
typedef __attribute__((ext_vector_type(4))) unsigned int uint4v;
typedef unsigned long long u64;

__device__ __forceinline__ float2v pk_fma(float2v a, float2v b, float2v c){
  return __builtin_elementwise_fma(a, b, c);
}
__device__ __forceinline__ float2v lo2(float4v v){ return (float2v){v[0], v[1]}; }
__device__ __forceinline__ float2v hi2(float4v v){ return (float2v){v[2], v[3]}; }

// pack 4 f32 -> 4 fp8 e4m3 bytes (ascending)
__device__ __forceinline__ unsigned pk4fp8(float v0, float v1, float v2, float v3){
  int w = __builtin_amdgcn_cvt_pk_fp8_f32(v0, v1, 0, false);
  w = __builtin_amdgcn_cvt_pk_fp8_f32(v2, v3, w, true);
  return (unsigned)w;
}
template<bool HI>
__device__ __forceinline__ float2v up2(unsigned w){
  return __builtin_amdgcn_cvt_pk_f32_fp8((int)w, HI);
}
__device__ __forceinline__ float4v mfma8(u64 a, u64 b, float4v c){
  return __builtin_amdgcn_mfma_f32_16x16x32_fp8_fp8((long)a, (long)b, c, 0, 0, 0);
}
// P16 = 16*Phi(z) (cubic Taylor), gp16 = 16*gelu'(z)
__device__ __forceinline__ void act2(float2v z, float2v& P16, float2v& gp16){
  const float2v c1v  = {6.3830764862829235f, 6.3830764862829235f};
  const float2v c3v  = {-1.0638460810704874f, -1.0638460810704874f};
  const float2v c33v = {-3.1915382432114624f, -3.1915382432114624f};
  const float2v v8   = {8.f, 8.f};
  float2v z2 = z * z;
  float2v u  = pk_fma(z2, c3v, c1v);
  P16 = pk_fma(z, u, v8);
  float2v Pd = pk_fma(z2, c33v, c1v);
  gp16 = pk_fma(z, Pd, P16);
}

__device__ __forceinline__ void gl2lds16(const unsigned char* g, unsigned char* l){
  __builtin_amdgcn_global_load_lds((const __attribute__((address_space(1))) unsigned int*)g,
                                   (__attribute__((address_space(3))) unsigned int*)l,
                                   16, 0, 0);
}

// ---- prep: Wh fp32 [side][term][L][k][n] -> fp8 image [net][L][n][c ^ (n&15)][j], W*16 ----
// 28 blocks (net,L). Phase A: coalesced f32 row reads -> fp8 -> LDS [k][n].
// Phase B: byte-gather transpose -> b64 row writes at swizzled chunk positions.
__global__ __launch_bounds__(256)
void prep_weights(const float* __restrict__ lWh,
                  const float* __restrict__ rWh,
                  unsigned char* __restrict__ wbf)
{
  __shared__ __align__(16) unsigned char T[IMGB];
  const int b = blockIdx.x;               // net*7 + L
  const int net = b / NLAYER, L = b % NLAYER;
  const int side = net >> 1, term = net & 1;
  const float* src = (side ? rWh : lWh) + (size_t)((term*NLAYER + L)*128)*128;
  const int t = threadIdx.x;
  {
    const int k = t >> 1, n0 = (t & 1)*64;
    const float* row = src + k*128 + n0;
    #pragma unroll
    for (int c4 = 0; c4 < 4; ++c4){
      float4v f0 = *(const float4v*)(row + c4*16);
      float4v f1 = *(const float4v*)(row + c4*16 + 4);
      float4v f2 = *(const float4v*)(row + c4*16 + 8);
      float4v f3 = *(const float4v*)(row + c4*16 + 12);
      uint4v wv = { pk4fp8(f0[0]*WSCALE, f0[1]*WSCALE, f0[2]*WSCALE, f0[3]*WSCALE),
                    pk4fp8(f1[0]*WSCALE, f1[1]*WSCALE, f1[2]*WSCALE, f1[3]*WSCALE),
                    pk4fp8(f2[0]*WSCALE, f2[1]*WSCALE, f2[2]*WSCALE, f2[3]*WSCALE),
                    pk4fp8(f3[0]*WSCALE, f3[1]*WSCALE, f3[2]*WSCALE, f3[3]*WSCALE) };
      *(uint4v*)&T[k*128 + n0 + c4*16] = wv;
    }
  }
  __syncthreads();
  {
    const int n = t >> 1, c0 = (t & 1)*8;
    const int sw = n & 15;
    unsigned char* dst = wbf + ((size_t)b << 14) + n*128;
    #pragma unroll
    for (int c = 0; c < 8; ++c){
      const int kc = (c0 + c)*8;
      u64 v = 0;
      #pragma unroll
      for (int j = 0; j < 8; ++j)
        v |= (u64)T[(kc + j)*128 + n] << (8*j);
      *(u64*)(dst + ((c0 + c) ^ sw)*8) = v;
    }
  }
}

__global__ __launch_bounds__(256, 4)
void sympl_main(const float* __restrict__ X,
                const float* __restrict__ lW0, const float* __restrict__ lb0,
                const float* __restrict__ lbh, const float* __restrict__ lWo,
                const float* __restrict__ rW0, const float* __restrict__ rb0,
                const float* __restrict__ rbh, const float* __restrict__ rWo,
                const int* __restrict__ lidx, const int* __restrict__ ridx,
                const unsigned char* __restrict__ wbf,
                float* __restrict__ out)
{
  __shared__ __align__(16) unsigned char sW[IMGB];   // 16 KB weight tile (A image)
  __shared__ __align__(16) unsigned char sH[8192];   // 8 KB acts: rows 0-31 S_h, 32-63 S_d
  // element row e, byte-chunk c: addr = e*128 + (c ^ (e&15))*8

  const int tid  = threadIdx.x;
  const int lane = tid & 63;
  const int w    = tid >> 6;
  const int m0   = lane & 15;
  const int q    = lane >> 4;
  const int g    = w & 1;          // element group (0:0-15, 1:16-31)
  const int ih   = w >> 1;         // n_out half (tiles ih*4 .. ih*4+3)
  const int col  = blockIdx.y;
  const int e0   = blockIdx.x * 32;
  const int r    = tid >> 3;       // element 0..31 (8 threads each)
  const int sg   = tid & 7;
  const int rs   = r & 15;

  const int lt = (lidx[0] == col) ? 0 : 1;
  const int rt = (ridx[0] == col) ? 0 : 1;

  float qv = X[(e0 + r)*4 + col];
  float pv = X[(e0 + r)*4 + 2 + col];

  const float dt = 0.1f;
  const float C0 = 0.6756035959798289f, C1 = -0.17560359597982883f;
  const float D0 = 1.3512071919596578f, D1 = -1.7024143839193153f;
  // fold 1/(16*4^7) = 1/262144 (final S_d scale) into the step coefficients
  const float is = 1.0f / 262144.0f;
  const float coefs[7] = { C0*dt*is, -D0*dt*is, C1*dt*is, -D1*dt*is,
                           C1*dt*is, -D0*dt*is, C0*dt*is };

  const float2v inv256v = {1.f/256.f, 1.f/256.f};
  const float2v inv64v  = {1.f/64.f, 1.f/64.f};

  // prologue: stage sW for ev=0 (right net, term rt, L=0)
  {
    const unsigned char* src = wbf + (size_t)(2 + rt)*NLAYER*IMGB;
    #pragma unroll
    for (int it = 0; it < 4; ++it){
      int o = (it*256 + tid) * 16;
      gl2lds16(src + o, sW + o);
    }
  }
  __syncthreads();

  for (int ev = 0; ev < 7; ++ev){
    const bool isT = !(ev & 1);
    const int  term = isT ? rt : lt;
    const float* W0p = (isT ? rW0 : lW0) + term*128;
    const float* b0p = (isT ? rb0 : lb0) + term*128;
    const float* bhp = (isT ? rbh : lbh) + term*NLAYER*128;
    const float* Wop = (isT ? rWo : lWo) + term*128;
    const unsigned char* wimg = wbf + (size_t)(((isT ? 2 : 0) + term)*NLAYER)*IMGB;
    const int tnx = (ev & 1) ? rt : lt;
    const unsigned char* wimg_nx = wbf + (size_t)((((ev & 1) ? 2 : 0) + tnx)*NLAYER)*IMGB;

    // ---- layer 0: S_h = 16*gelu(z), S_d = 16*gelu'(z)*w, z = x*w+b ----
    {
      const float x = isT ? pv : qv;
      const float2v xv = {x, x};
      unsigned char* pH = sH + r*128;
      unsigned char* pD = pH + 32*128;
      #pragma unroll
      for (int c = 0; c < 2; ++c){
        int n0 = sg*16 + c*8;
        float4v wa = *(const float4v*)(W0p + n0);
        float4v wb = *(const float4v*)(W0p + n0 + 4);
        float4v ba = *(const float4v*)(b0p + n0);
        float4v bb = *(const float4v*)(b0p + n0 + 4);
        float2v zp[4] = { pk_fma(xv, lo2(wa), lo2(ba)), pk_fma(xv, hi2(wa), hi2(ba)),
                          pk_fma(xv, lo2(wb), lo2(bb)), pk_fma(xv, hi2(wb), hi2(bb)) };
        float2v wp[4] = { lo2(wa), hi2(wa), lo2(wb), hi2(wb) };
        float Sh[8], Sd[8];
        #pragma unroll
        for (int pp = 0; pp < 4; ++pp){
          float2v P16, gp16; act2(zp[pp], P16, gp16);
          float2v h = zp[pp] * P16;
          float2v d = gp16 * wp[pp];
          Sh[pp*2] = h[0]; Sh[pp*2+1] = h[1];
          Sd[pp*2] = d[0]; Sd[pp*2+1] = d[1];
        }
        u64 hv = (u64)pk4fp8(Sh[0],Sh[1],Sh[2],Sh[3]) | ((u64)pk4fp8(Sh[4],Sh[5],Sh[6],Sh[7]) << 32);
        u64 dv = (u64)pk4fp8(Sd[0],Sd[1],Sd[2],Sd[3]) | ((u64)pk4fp8(Sd[4],Sd[5],Sd[6],Sd[7]) << 32);
        int off = ((2*sg + c) ^ rs) * 8;
        *(u64*)(pH + off) = hv;
        *(u64*)(pD + off) = dv;
      }
    }
    __syncthreads();

    const unsigned char* pB0 = sH + (g*16 + m0)*128;
    const unsigned char* pB1 = pB0 + 32*128;
    const unsigned char* pA  = sW + (ih*64 + m0)*128;
    unsigned char* pHe = sH + (g*16 + m0)*128;
    unsigned char* pDe = pHe + 32*128;

    // ---- hidden layers ----
    for (int L = 0; L < NLAYER; ++L){
      float4v acc[4][2];
      #pragma unroll
      for (int i = 0; i < 4; ++i){
        acc[i][0] = (float4v){0.f,0.f,0.f,0.f};
        acc[i][1] = (float4v){0.f,0.f,0.f,0.f};
      }
      #pragma unroll
      for (int ks = 0; ks < 4; ++ks){
        const int co = ((ks*4 + q) ^ m0) * 8;
        u64 b0 = *(const u64*)(pB0 + co);
        u64 b1 = *(const u64*)(pB1 + co);
        #pragma unroll
        for (int i = 0; i < 4; ++i){
          u64 a = *(const u64*)(pA + i*2048 + co);
          acc[i][0] = mfma8(a, b0, acc[i][0]);
          acc[i][1] = mfma8(a, b1, acc[i][1]);
        }
      }
      __syncthreads();   // all sW/sH reads done

      // stage next weight tile (async; drained by next barrier's vmcnt)
      if (!(ev == 6 && L == 6)){
        const unsigned char* nsrc = (L < 6) ? (wimg + (size_t)(L+1)*IMGB) : wimg_nx;
        #pragma unroll
        for (int it = 0; it < 4; ++it){
          int o = (it*256 + tid) * 16;
          gl2lds16(nsrc + o, sW + o);
        }
      }

      // epilogue: z = acc0/256 + b; S_h' = z*P16; S_d' = gp16 * (acc1/64)  [d-scale *4/layer]
      const float* bias = bhp + L*128;
      const bool last = (L == NLAYER-1);
      #pragma unroll
      for (int i = 0; i < 4; ++i){
        const int I = ih*4 + i;
        float4v bv = *(const float4v*)(bias + I*16 + q*4);
        float2v za = pk_fma(lo2(acc[i][0]), inv256v, lo2(bv));
        float2v zb = pk_fma(hi2(acc[i][0]), inv256v, hi2(bv));
        float2v ta = lo2(acc[i][1]) * inv64v;
        float2v tb = hi2(acc[i][1]) * inv64v;
        float2v Pa, ga, Pb, gb;
        act2(za, Pa, ga);
        act2(zb, Pb, gb);
        float2v ha = za * Pa, hb = zb * Pb;
        float2v da = ga * ta, db = gb * tb;
        const int off = ((I*2 + (q >> 1)) ^ m0) * 8 + (q & 1) * 4;
        if (!last) *(unsigned*)(pHe + off) = pk4fp8(ha[0], ha[1], hb[0], hb[1]);
        *(unsigned*)(pDe + off) = pk4fp8(da[0], da[1], db[0], db[1]);
      }
      __syncthreads();   // sH(L+1) ready; staged sW drained
    }

    // ---- reduce: s_raw = S_d7 . Wo  (= 262144 * s) ----
    {
      const unsigned char* pD = sH + (32 + r)*128;
      float2v sv = {0.f, 0.f};
      #pragma unroll
      for (int c = 0; c < 2; ++c){
        u64 dv8 = *(const u64*)(pD + ((2*sg + c) ^ rs) * 8);
        unsigned wlo = (unsigned)dv8, whi = (unsigned)(dv8 >> 32);
        float4v woa = *(const float4v*)(Wop + sg*16 + c*8);
        float4v wob = *(const float4v*)(Wop + sg*16 + c*8 + 4);
        sv = pk_fma(up2<false>(wlo), lo2(woa), sv);
        sv = pk_fma(up2<true>(wlo),  hi2(woa), sv);
        sv = pk_fma(up2<false>(whi), lo2(wob), sv);
        sv = pk_fma(up2<true>(whi),  hi2(wob), sv);
      }
      float s = sv[0] + sv[1];
      s += __shfl_xor(s, 1);
      s += __shfl_xor(s, 2);
      s += __shfl_xor(s, 4);
      if (isT) qv += coefs[ev] * s;
      else     pv += coefs[ev] * s;
    }
    __syncthreads();   // reduce reads done before next eval's layer-0 writes
  }

  if (sg == 0){
    out[(e0 + r)*4 + col]     = qv;
    out[(e0 + r)*4 + 2 + col] = pv;
  }
}

extern "C" void kernel_launch(void* const* d_in, const int* in_sizes, int n_in,
                              void* d_out, int out_size, void* d_ws, size_t ws_size,
                              hipStream_t stream)
{
  const float* X   = (const float*)d_in[0];
  const float* lW0 = (const float*)d_in[1];
  const float* lb0 = (const float*)d_in[2];
  const float* lWh = (const float*)d_in[3];
  const float* lbh = (const float*)d_in[4];
  const float* lWo = (const float*)d_in[5];
  const float* rW0 = (const float*)d_in[7];
  const float* rb0 = (const float*)d_in[8];
  const float* rWh = (const float*)d_in[9];
  const float* rbh = (const float*)d_in[10];
  const float* rWo = (const float*)d_in[11];
  const int*   li  = (const int*)d_in[13];
  const int*   ri  = (const int*)d_in[14];
  unsigned char* wbf = (unsigned char*)d_ws;   // 4*7*16384 B = 458752 B
  float* out = (float*)d_out;
  const int B = in_sizes[0] / 4;

  hipLaunchKernelGGL(prep_weights, dim3(4*NLAYER), dim3(256), 0, stream,
                     lWh, rWh, wbf);
  hipLaunchKernelGGL(sympl_main, dim3(B/32, 2), dim3(256), 0, stream,
                     X, lW0, lb0, lbh, lWo, rW0, rb0, rbh, rWo, li, ri, wbf, out);
}

// Round 7
// 197.592 us; speedup vs baseline: 2.3945x; 1.0276x over previous
//
#include <hip/hip_runtime.h>

#define NLAYER 7
#define IMGB 16384          // bytes per weight-layer image: A[n][k] fp8, 8B-chunk XOR-swizzled
#define WSCALE 16.0f        // weights stored x16 (e4m3 subnormal protection)

typedef __attribute__((ext_vector_type(2))) float float2v;
typedef __attribute__((ext_vector_type(4))) float float4v;
typedef __attribute__((ext_vector_type(4))) unsigned int uint4v;
typedef __attribute__((ext_vector_type(8))) int int8v;
typedef unsigned long long u64;

__device__ __forceinline__ float2v pk_fma(float2v a, float2v b, float2v c){
  return __builtin_elementwise_fma(a, b, c);
}
__device__ __forceinline__ float2v lo2(float4v v){ return (float2v){v[0], v[1]}; }
__device__ __forceinline__ float2v hi2(float4v v){ return (float2v){v[2], v[3]}; }

// pack 4 f32 -> 4 fp8 e4m3 bytes (ascending)
__device__ __forceinline__ unsigned pk4fp8(float v0, float v1, float v2, float v3){
  int w = __builtin_amdgcn_cvt_pk_fp8_f32(v0, v1, 0, false);
  w = __builtin_amdgcn_cvt_pk_fp8_f32(v2, v3, w, true);
  return (unsigned)w;
}
template<bool HI>
__device__ __forceinline__ float2v up2(unsigned w){
  return __builtin_amdgcn_cvt_pk_f32_fp8((int)w, HI);
}
// MX-scaled MFMA, K=128, FMT=fp8 e4m3 both operands, scales = 1.0 (E8M0 0x7F)
__device__ __forceinline__ float4v mfma128(int8v a, int8v b){
  return __builtin_amdgcn_mfma_scale_f32_16x16x128_f8f6f4(
      a, b, (float4v){0.f,0.f,0.f,0.f}, 0, 0, 0, 0x7F7F7F7F, 0, 0x7F7F7F7F);
}
// P16 = 16*Phi(z) (cubic Taylor), gp16 = 16*gelu'(z)
__device__ __forceinline__ void act2(float2v z, float2v& P16, float2v& gp16){
  const float2v c1v  = {6.3830764862829235f, 6.3830764862829235f};
  const float2v c3v  = {-1.0638460810704874f, -1.0638460810704874f};
  const float2v c33v = {-3.1915382432114624f, -3.1915382432114624f};
  const float2v v8   = {8.f, 8.f};
  float2v z2 = z * z;
  float2v u  = pk_fma(z2, c3v, c1v);
  P16 = pk_fma(z, u, v8);
  float2v Pd = pk_fma(z2, c33v, c1v);
  gp16 = pk_fma(z, Pd, P16);
}

__device__ __forceinline__ void gl2lds16(const unsigned char* g, unsigned char* l){
  __builtin_amdgcn_global_load_lds((const __attribute__((address_space(1))) unsigned int*)g,
                                   (__attribute__((address_space(3))) unsigned int*)l,
                                   16, 0, 0);
}

// operand gather: 32 contiguous k-bytes (kgroup q) from a swizzled LDS row
__device__ __forceinline__ int8v ld_op(const unsigned char* row, int q, int m0){
  u64 x0 = *(const u64*)(row + (((4*q+0) ^ m0)*8));
  u64 x1 = *(const u64*)(row + (((4*q+1) ^ m0)*8));
  u64 x2 = *(const u64*)(row + (((4*q+2) ^ m0)*8));
  u64 x3 = *(const u64*)(row + (((4*q+3) ^ m0)*8));
  int8v v;
  v[0]=(int)x0; v[1]=(int)(x0>>32);
  v[2]=(int)x1; v[3]=(int)(x1>>32);
  v[4]=(int)x2; v[5]=(int)(x2>>32);
  v[6]=(int)x3; v[7]=(int)(x3>>32);
  return v;
}

// ---- prep: Wh fp32 [side][term][L][k][n] -> fp8 image [net][L][n][c ^ (n&15)][j], W*16 ----
__global__ __launch_bounds__(256)
void prep_weights(const float* __restrict__ lWh,
                  const float* __restrict__ rWh,
                  unsigned char* __restrict__ wbf)
{
  __shared__ __align__(16) unsigned char T[IMGB];
  const int b = blockIdx.x;               // net*7 + L
  const int net = b / NLAYER, L = b % NLAYER;
  const int side = net >> 1, term = net & 1;
  const float* src = (side ? rWh : lWh) + (size_t)((term*NLAYER + L)*128)*128;
  const int t = threadIdx.x;
  {
    const int k = t >> 1, n0 = (t & 1)*64;
    const float* row = src + k*128 + n0;
    #pragma unroll
    for (int c4 = 0; c4 < 4; ++c4){
      float4v f0 = *(const float4v*)(row + c4*16);
      float4v f1 = *(const float4v*)(row + c4*16 + 4);
      float4v f2 = *(const float4v*)(row + c4*16 + 8);
      float4v f3 = *(const float4v*)(row + c4*16 + 12);
      uint4v wv = { pk4fp8(f0[0]*WSCALE, f0[1]*WSCALE, f0[2]*WSCALE, f0[3]*WSCALE),
                    pk4fp8(f1[0]*WSCALE, f1[1]*WSCALE, f1[2]*WSCALE, f1[3]*WSCALE),
                    pk4fp8(f2[0]*WSCALE, f2[1]*WSCALE, f2[2]*WSCALE, f2[3]*WSCALE),
                    pk4fp8(f3[0]*WSCALE, f3[1]*WSCALE, f3[2]*WSCALE, f3[3]*WSCALE) };
      *(uint4v*)&T[k*128 + n0 + c4*16] = wv;
    }
  }
  __syncthreads();
  {
    const int n = t >> 1, c0 = (t & 1)*8;
    const int sw = n & 15;
    unsigned char* dst = wbf + ((size_t)b << 14) + n*128;
    #pragma unroll
    for (int c = 0; c < 8; ++c){
      const int kc = (c0 + c)*8;
      u64 v = 0;
      #pragma unroll
      for (int j = 0; j < 8; ++j)
        v |= (u64)T[(kc + j)*128 + n] << (8*j);
      *(u64*)(dst + ((c0 + c) ^ sw)*8) = v;
    }
  }
}

__global__ __launch_bounds__(256, 4)
void sympl_main(const float* __restrict__ X,
                const float* __restrict__ lW0, const float* __restrict__ lb0,
                const float* __restrict__ lbh, const float* __restrict__ lWo,
                const float* __restrict__ rW0, const float* __restrict__ rb0,
                const float* __restrict__ rbh, const float* __restrict__ rWo,
                const int* __restrict__ lidx, const int* __restrict__ ridx,
                const unsigned char* __restrict__ wbf,
                float* __restrict__ out)
{
  __shared__ __align__(16) unsigned char sW[IMGB];   // 16 KB weight tile (A image)
  __shared__ __align__(16) unsigned char sH[8192];   // 8 KB acts: rows 0-31 S_h, 32-63 S_d
  // element row e, byte-chunk c: addr = e*128 + (c ^ (e&15))*8

  const int tid  = threadIdx.x;
  const int lane = tid & 63;
  const int w    = tid >> 6;
  const int m0   = lane & 15;
  const int q    = lane >> 4;
  const int g    = w & 1;          // element group (0:0-15, 1:16-31)
  const int ih   = w >> 1;         // n_out half (tiles ih*4 .. ih*4+3)
  const int col  = blockIdx.y;
  const int e0   = blockIdx.x * 32;
  const int r    = tid >> 3;       // element 0..31 (8 threads each)
  const int sg   = tid & 7;
  const int rs   = r & 15;

  const int lt = (lidx[0] == col) ? 0 : 1;
  const int rt = (ridx[0] == col) ? 0 : 1;

  float qv = X[(e0 + r)*4 + col];
  float pv = X[(e0 + r)*4 + 2 + col];

  const float dt = 0.1f;
  const float C0 = 0.6756035959798289f, C1 = -0.17560359597982883f;
  const float D0 = 1.3512071919596578f, D1 = -1.7024143839193153f;
  // fold 1/(16*4^7) = 1/262144 (final S_d scale) into the step coefficients
  const float is = 1.0f / 262144.0f;
  const float coefs[7] = { C0*dt*is, -D0*dt*is, C1*dt*is, -D1*dt*is,
                           C1*dt*is, -D0*dt*is, C0*dt*is };

  const float2v inv256v = {1.f/256.f, 1.f/256.f};
  const float2v inv64v  = {1.f/64.f, 1.f/64.f};

  // prologue: stage sW for ev=0 (right net, term rt, L=0)
  {
    const unsigned char* src = wbf + (size_t)(2 + rt)*NLAYER*IMGB;
    #pragma unroll
    for (int it = 0; it < 4; ++it){
      int o = (it*256 + tid) * 16;
      gl2lds16(src + o, sW + o);
    }
  }
  __syncthreads();

  for (int ev = 0; ev < 7; ++ev){
    const bool isT = !(ev & 1);
    const int  term = isT ? rt : lt;
    const float* W0p = (isT ? rW0 : lW0) + term*128;
    const float* b0p = (isT ? rb0 : lb0) + term*128;
    const float* bhp = (isT ? rbh : lbh) + term*NLAYER*128;
    const float* Wop = (isT ? rWo : lWo) + term*128;
    const unsigned char* wimg = wbf + (size_t)(((isT ? 2 : 0) + term)*NLAYER)*IMGB;
    const int tnx = (ev & 1) ? rt : lt;
    const unsigned char* wimg_nx = wbf + (size_t)((((ev & 1) ? 2 : 0) + tnx)*NLAYER)*IMGB;

    // ---- layer 0: S_h = 16*gelu(z), S_d = 16*gelu'(z)*w, z = x*w+b ----
    {
      const float x = isT ? pv : qv;
      const float2v xv = {x, x};
      unsigned char* pH = sH + r*128;
      unsigned char* pD = pH + 32*128;
      #pragma unroll
      for (int c = 0; c < 2; ++c){
        int n0 = sg*16 + c*8;
        float4v wa = *(const float4v*)(W0p + n0);
        float4v wb = *(const float4v*)(W0p + n0 + 4);
        float4v ba = *(const float4v*)(b0p + n0);
        float4v bb = *(const float4v*)(b0p + n0 + 4);
        float2v zp[4] = { pk_fma(xv, lo2(wa), lo2(ba)), pk_fma(xv, hi2(wa), hi2(ba)),
                          pk_fma(xv, lo2(wb), lo2(bb)), pk_fma(xv, hi2(wb), hi2(bb)) };
        float2v wp[4] = { lo2(wa), hi2(wa), lo2(wb), hi2(wb) };
        float Sh[8], Sd[8];
        #pragma unroll
        for (int pp = 0; pp < 4; ++pp){
          float2v P16, gp16; act2(zp[pp], P16, gp16);
          float2v h = zp[pp] * P16;
          float2v d = gp16 * wp[pp];
          Sh[pp*2] = h[0]; Sh[pp*2+1] = h[1];
          Sd[pp*2] = d[0]; Sd[pp*2+1] = d[1];
        }
        u64 hv = (u64)pk4fp8(Sh[0],Sh[1],Sh[2],Sh[3]) | ((u64)pk4fp8(Sh[4],Sh[5],Sh[6],Sh[7]) << 32);
        u64 dv = (u64)pk4fp8(Sd[0],Sd[1],Sd[2],Sd[3]) | ((u64)pk4fp8(Sd[4],Sd[5],Sd[6],Sd[7]) << 32);
        int off = ((2*sg + c) ^ rs) * 8;
        *(u64*)(pH + off) = hv;
        *(u64*)(pD + off) = dv;
      }
    }
    __syncthreads();

    const unsigned char* pB0 = sH + (g*16 + m0)*128;
    const unsigned char* pB1 = pB0 + 32*128;
    const unsigned char* pA  = sW + (ih*64 + m0)*128;
    unsigned char* pHe = sH + (g*16 + m0)*128;
    unsigned char* pDe = pHe + 32*128;

    // ---- hidden layers: one K=128 MX mfma per (tile,stream) ----
    for (int L = 0; L < NLAYER; ++L){
      int8v b0 = ld_op(pB0, q, m0);
      int8v b1 = ld_op(pB1, q, m0);
      float4v acc[4][2];
      #pragma unroll
      for (int i = 0; i < 4; ++i){
        int8v a = ld_op(pA + i*2048, q, m0);
        acc[i][0] = mfma128(a, b0);
        acc[i][1] = mfma128(a, b1);
      }
      __syncthreads();   // all sW/sH reads done

      // stage next weight tile (async; drained by next barrier's vmcnt)
      if (!(ev == 6 && L == 6)){
        const unsigned char* nsrc = (L < 6) ? (wimg + (size_t)(L+1)*IMGB) : wimg_nx;
        #pragma unroll
        for (int it = 0; it < 4; ++it){
          int o = (it*256 + tid) * 16;
          gl2lds16(nsrc + o, sW + o);
        }
      }

      // epilogue: z = acc0/256 + b; S_h' = z*P16; S_d' = gp16 * (acc1/64)  [d-scale *4/layer]
      const float* bias = bhp + L*128;
      const bool last = (L == NLAYER-1);
      #pragma unroll
      for (int i = 0; i < 4; ++i){
        const int I = ih*4 + i;
        float4v bv = *(const float4v*)(bias + I*16 + q*4);
        float2v za = pk_fma(lo2(acc[i][0]), inv256v, lo2(bv));
        float2v zb = pk_fma(hi2(acc[i][0]), inv256v, hi2(bv));
        float2v ta = lo2(acc[i][1]) * inv64v;
        float2v tb = hi2(acc[i][1]) * inv64v;
        float2v Pa, ga, Pb, gb;
        act2(za, Pa, ga);
        act2(zb, Pb, gb);
        float2v ha = za * Pa, hb = zb * Pb;
        float2v da = ga * ta, db = gb * tb;
        const int off = ((I*2 + (q >> 1)) ^ m0) * 8 + (q & 1) * 4;
        if (!last) *(unsigned*)(pHe + off) = pk4fp8(ha[0], ha[1], hb[0], hb[1]);
        *(unsigned*)(pDe + off) = pk4fp8(da[0], da[1], db[0], db[1]);
      }
      __syncthreads();   // sH(L+1) ready; staged sW drained
    }

    // ---- reduce: s_raw = S_d7 . Wo  (= 262144 * s) ----
    {
      const unsigned char* pD = sH + (32 + r)*128;
      float2v sv = {0.f, 0.f};
      #pragma unroll
      for (int c = 0; c < 2; ++c){
        u64 dv8 = *(const u64*)(pD + ((2*sg + c) ^ rs) * 8);
        unsigned wlo = (unsigned)dv8, whi = (unsigned)(dv8 >> 32);
        float4v woa = *(const float4v*)(Wop + sg*16 + c*8);
        float4v wob = *(const float4v*)(Wop + sg*16 + c*8 + 4);
        sv = pk_fma(up2<false>(wlo), lo2(woa), sv);
        sv = pk_fma(up2<true>(wlo),  hi2(woa), sv);
        sv = pk_fma(up2<false>(whi), lo2(wob), sv);
        sv = pk_fma(up2<true>(whi),  hi2(wob), sv);
      }
      float s = sv[0] + sv[1];
      s += __shfl_xor(s, 1);
      s += __shfl_xor(s, 2);
      s += __shfl_xor(s, 4);
      if (isT) qv += coefs[ev] * s;
      else     pv += coefs[ev] * s;
    }
    __syncthreads();   // reduce reads done before next eval's layer-0 writes
  }

  if (sg == 0){
    out[(e0 + r)*4 + col]     = qv;
    out[(e0 + r)*4 + 2 + col] = pv;
  }
}

extern "C" void kernel_launch(void* const* d_in, const int* in_sizes, int n_in,
                              void* d_out, int out_size, void* d_ws, size_t ws_size,
                              hipStream_t stream)
{
  const float* X   = (const float*)d_in[0];
  const float* lW0 = (const float*)d_in[1];
  const float* lb0 = (const float*)d_in[2];
  const float* lWh = (const float*)d_in[3];
  const float* lbh = (const float*)d_in[4];
  const float* lWo = (const float*)d_in[5];
  const float* rW0 = (const float*)d_in[7];
  const float* rb0 = (const float*)d_in[8];
  const float* rWh = (const float*)d_in[9];
  const float* rbh = (const float*)d_in[10];
  const float* rWo = (const float*)d_in[11];
  const int*   li  = (const int*)d_in[13];
  const int*   ri  = (const int*)d_in[14];
  unsigned char* wbf = (unsigned char*)d_ws;   // 4*7*16384 B = 458752 B
  float* out = (float*)d_out;
  const int B = in_sizes[0] / 4;

  hipLaunchKernelGGL(prep_weights, dim3(4*NLAYER), dim3(256), 0, stream,
                     lWh, rWh, wbf);
  hipLaunchKernelGGL(sympl_main, dim3(B/32, 2), dim3(256), 0, stream,
                     X, lW0, lb0, lbh, lWo, rW0, rb0, rbh, rWo, li, ri, wbf, out);
}